// Round 4
// baseline (343.044 us; speedup 1.0000x reference)
//
#include <hip/hip_runtime.h>
#include <hip/hip_bf16.h>

typedef __bf16 bf16;
typedef __bf16 bf16x8 __attribute__((ext_vector_type(8)));
typedef __bf16 bf16x4 __attribute__((ext_vector_type(4)));
typedef float  f32x4  __attribute__((ext_vector_type(4)));

#define MFMA16(A, B, C) __builtin_amdgcn_mfma_f32_16x16x32_bf16((A), (B), (C), 0, 0, 0)

static constexpr int Bn = 4;
static constexpr int T  = 4096;
static constexpr int Cd = 1024;
static constexpr int H  = 64;
static constexpr int NG = 192;
static constexpr int CH = 8;            // K-tiles (64 keys each) per split-K chunk
static constexpr int SLOTS_PER_B = 288; // sum_{qt=0..63} ceil((qt+1)/8)
// q pre-scale: 1/sqrt(C) * log2(e) so attn can use v_exp_f32 (2^x) directly
static constexpr float QSCALE = 0.045084220f;

// async global->LDS DMA, 16B per lane; LDS dest = wave-uniform base + lane*16
__device__ inline void dma16(const void* g, void* l) {
    __builtin_amdgcn_global_load_lds(
        (const __attribute__((address_space(1))) unsigned int*)g,
        (__attribute__((address_space(3))) unsigned int*)l, 16, 0, 0);
}

// compile-time-constant counted vmcnt (folds to one instruction after unroll)
__device__ __forceinline__ void waitcnt_vm(int n) {
    if (n == 0)      asm volatile("s_waitcnt vmcnt(0)" ::: "memory");
    else if (n == 1) asm volatile("s_waitcnt vmcnt(1)" ::: "memory");
    else             asm volatile("s_waitcnt vmcnt(2)" ::: "memory");
}

__device__ inline bf16x8 cvt_bf16x8(float4 a, float4 b) {
    bf16x8 r;
    r[0] = (bf16)a.x; r[1] = (bf16)a.y; r[2] = (bf16)a.z; r[3] = (bf16)a.w;
    r[4] = (bf16)b.x; r[5] = (bf16)b.y; r[6] = (bf16)b.z; r[7] = (bf16)b.w;
    return r;
}

// ---------------------------------------------------------------------------
// Kernel 1: coalesced transpose W=[Wq|Wk|Wv] ([C][H] fp32) -> Wt[192][1024] bf16
// Also zeroes the split-K arrival counters (workspace poison is non-zero;
// stream order guarantees visibility to attn_kernel).
// ---------------------------------------------------------------------------
__global__ __launch_bounds__(256) void wt_kernel(const float* __restrict__ Wq,
                                                 const float* __restrict__ Wk,
                                                 const float* __restrict__ Wv,
                                                 bf16* __restrict__ Wt,
                                                 int* __restrict__ cnt) {
    if (blockIdx.x == 0 && blockIdx.y == 0) cnt[threadIdx.x] = 0;  // 256 = Bn*64
    __shared__ float s[64][65];
    const int cb = blockIdx.x;
    const int m  = blockIdx.y;
    const float* W = (m == 0) ? Wq : (m == 1) ? Wk : Wv;
    for (int i = threadIdx.x; i < 64 * 64; i += 256) {
        const int c = i >> 6, h = i & 63;
        s[c][h] = W[(cb * 64 + c) * H + h];
    }
    __syncthreads();
    for (int i = threadIdx.x; i < 64 * 64; i += 256) {
        const int n = i >> 6, c = i & 63;
        Wt[(m * 64 + n) * Cd + cb * 64 + c] = (bf16)s[c][n];
    }
}

// ---------------------------------------------------------------------------
// Kernel 2: QKV projection v8 (unchanged — at its x-HBM/MFMA floor).
// ---------------------------------------------------------------------------
__global__ __launch_bounds__(512, 4) void proj_kernel(const float* __restrict__ x,
                                                      const bf16* __restrict__ Wt,
                                                      bf16* __restrict__ qw,
                                                      bf16* __restrict__ kw,
                                                      bf16* __restrict__ vtw) {
    const int tid  = threadIdx.x;
    const int lane = tid & 63;
    const int w    = tid >> 6;       // 0..7
    const int wr   = w >> 2;         // 0..1 row-group
    const int wc   = w & 3;          // 0..3 col-group
    const int ml   = lane & 15;
    const int quad = lane >> 4;

    const long r0 = (long)blockIdx.x * 32;

    __shared__ float sX[4][32][64];   // 8 KB/slot x4, 16B chunks swizzled c^(r&15)
    __shared__ bf16  sW[2][192][64];  // 24 KB/buf x2, 16B chunks swizzled c^(r&7)

    const int xrow = w * 4 + (lane >> 4);           // 0..31
    const float* gx = x + (r0 + xrow) * Cd + (((lane & 15) ^ (xrow & 15)) << 2);
    const int wchunk = ((lane & 7) ^ (lane >> 3)) << 3;   // elem offset in tile
    const bf16* gw0 = Wt + (long)(w * 24 + 0 + (lane >> 3)) * Cd + wchunk;
    const bf16* gw1 = Wt + (long)(w * 24 + 8 + (lane >> 3)) * Cd + wchunk;
    const bf16* gw2 = Wt + (long)(w * 24 + 16 + (lane >> 3)) * Cd + wchunk;

    f32x4 acc[3];
    #pragma unroll
    for (int j = 0; j < 3; ++j) acc[j] = f32x4{0.f, 0.f, 0.f, 0.f};

    // prologue issue order matters for vmcnt accounting: x(0), w(0)x3, x(1), x(2)
    dma16(gx, &sX[0][w * 4][0]);
    dma16(gw0, &sW[0][w * 24 + 0][0]);
    dma16(gw1, &sW[0][w * 24 + 8][0]);
    dma16(gw2, &sW[0][w * 24 + 16][0]);
    dma16(gx + 64,  &sX[1][w * 4][0]);
    dma16(gx + 128, &sX[2][w * 4][0]);

    const int arow = wr * 16 + ml;                  // A row in tile
    const int brow0 = wc * 48 + ml;                 // B rows in tile (f*16 +)
    const int bsw = ml & 7;

    #pragma unroll
    for (int t = 0; t < 16; ++t) {
        waitcnt_vm(t == 0 ? 2 : (t <= 13 ? 1 : 0));
        __builtin_amdgcn_sched_barrier(0);
        __builtin_amdgcn_s_barrier();           // tile t ready in all waves
        __builtin_amdgcn_sched_barrier(0);

        if (t + 1 < 16) {
            dma16(gw0 + (t + 1) * 64, &sW[(t + 1) & 1][w * 24 + 0][0]);
            dma16(gw1 + (t + 1) * 64, &sW[(t + 1) & 1][w * 24 + 8][0]);
            dma16(gw2 + (t + 1) * 64, &sW[(t + 1) & 1][w * 24 + 16][0]);
        }
        if (t + 3 < 16) dma16(gx + (t + 3) * 64, &sX[(t + 3) & 3][w * 4][0]);

        const int bx = t & 3, bw = t & 1;
        __builtin_amdgcn_s_setprio(1);
        #pragma unroll
        for (int ks = 0; ks < 2; ++ks) {
            const int ca = (ks * 8 + quad * 2) ^ ml;       // A chunk (of 16)
            const float4 lo = *(const float4*)&sX[bx][arow][ca << 2];
            const float4 hi = *(const float4*)&sX[bx][arow][(ca ^ 1) << 2];
            const bf16x8 af = cvt_bf16x8(lo, hi);
            const int cb0 = (ks * 4 + quad) ^ bsw;         // B chunk (of 8)
            acc[0] = MFMA16(af, *(const bf16x8*)&sW[bw][brow0 + 0][cb0 << 3], acc[0]);
            acc[1] = MFMA16(af, *(const bf16x8*)&sW[bw][brow0 + 16][cb0 << 3], acc[1]);
            acc[2] = MFMA16(af, *(const bf16x8*)&sW[bw][brow0 + 32][cb0 << 3], acc[2]);
        }
        __builtin_amdgcn_s_setprio(0);
    }

    const int b = (int)(r0 >> 12);
    const long rowb = r0 + wr * 16 + quad * 4;
    const int  tloc = (int)(rowb & 4095);

    #pragma unroll
    for (int f = 0; f < 3; ++f) {
        const int base = wc * 48 + f * 16;
        const int sel  = base >> 6;
        const int h    = (base & 63) + ml;
        if (sel == 0) {
            #pragma unroll
            for (int rr = 0; rr < 4; ++rr)
                qw[(rowb + rr) * H + h] = (bf16)(acc[f][rr] * QSCALE);
        } else if (sel == 1) {
            #pragma unroll
            for (int rr = 0; rr < 4; ++rr)
                kw[(rowb + rr) * H + h] = (bf16)acc[f][rr];
        } else {
            bf16x4 pv;
            #pragma unroll
            for (int rr = 0; rr < 4; ++rr) pv[rr] = (bf16)acc[f][rr];
            *(bf16x4*)(vtw + ((long)(b * H + h)) * T + tloc) = pv;
        }
    }
}

// ---------------------------------------------------------------------------
// Kernel 3: split-K causal flash chunk v6 — combine FUSED (last block of each
// qt reduces all chunks; per-qt device-scope atomic counter + threadfence
// release/acquire). g==0 (single chunk) writes normalized output directly,
// skipping pO/pL. Deterministic: reducer sums chunks in index order.
// ---------------------------------------------------------------------------
__global__ __launch_bounds__(256, 4) void attn_kernel(const bf16* __restrict__ qw,
                                                      const bf16* __restrict__ kw,
                                                      const bf16* __restrict__ vtw,
                                                      float* __restrict__ pO,
                                                      float* __restrict__ pL,
                                                      int* __restrict__ cnt,
                                                      float* __restrict__ out) {
    // triangular decode: u in [0,36) -> (g, c) with c <= g
    const int u = blockIdx.x;
    int g = 0;
    #pragma unroll
    for (int gg = 1; gg < 8; ++gg) if (u >= (gg * (gg + 1)) / 2) g = gg;
    const int c  = u - (g * (g + 1)) / 2;
    const int r  = blockIdx.y;
    const int b  = blockIdx.z;
    const int qt = g * 8 + r;

    const int tid  = threadIdx.x;
    const int lane = tid & 63;
    const int w    = tid >> 6;
    const int ml   = lane & 15;
    const int quad = lane >> 4;
    const int mx   = ml & 7;

    __shared__ bf16 sK[2][64][64];    // 16 KB
    __shared__ bf16 sVt[2][64][64];   // 16 KB
    __shared__ bf16 sP[4][16][64];    // 8 KB, XOR chunk-swizzled (no pad)
    __shared__ int s_old;

    const int t0 = qt * 64;

    const bf16* q0 = qw + ((long)b * T + t0 + w * 16 + ml) * H;
    const bf16x8 aq0 = *(const bf16x8*)(q0 + quad * 8);
    const bf16x8 aq1 = *(const bf16x8*)(q0 + 32 + quad * 8);

    f32x4 O[4];
    #pragma unroll
    for (int ht = 0; ht < 4; ++ht) O[ht] = f32x4{0.f, 0.f, 0.f, 0.f};
    float lrow[4] = {0.f, 0.f, 0.f, 0.f};

    const int trow = t0 + w * 16 + quad * 4;
    const int jt0 = c * CH;
    const int jt1 = (c == g) ? qt + 1 : (c + 1) * CH;

    const int drow = w * 8 + (lane >> 3);
    const int dsw  = ((lane & 7) ^ (drow & 7)) << 3;
    const bf16* kbase = kw + (long)b * T * H;
    const bf16* vbase = vtw + (long)b * H * T;
    const long koffA = (long)drow * H + dsw;
    const long koffB = koffA + 32 * H;
    const long voffA = (long)drow * T + dsw;
    const long voffB = voffA + (long)32 * T;

    {   // prologue: issue tile jt0 (4 DMA per wave; waited inside the loop)
        const long ks0 = (long)jt0 * 64;
        dma16(kbase + ks0 * H + koffA, &sK[0][w * 8][0]);
        dma16(kbase + ks0 * H + koffB, &sK[0][32 + w * 8][0]);
        dma16(vbase + ks0 + voffA, &sVt[0][w * 8][0]);
        dma16(vbase + ks0 + voffB, &sVt[0][32 + w * 8][0]);
    }

    int buf = 0;
    for (int jt = jt0; jt < jt1; ++jt) {
        asm volatile("s_waitcnt vmcnt(0)" ::: "memory");
        __builtin_amdgcn_sched_barrier(0);
        __builtin_amdgcn_s_barrier();
        __builtin_amdgcn_sched_barrier(0);

        if (jt + 1 < jt1) {
            const long ksn = (long)(jt + 1) * 64;
            dma16(kbase + ksn * H + koffA, &sK[buf ^ 1][w * 8][0]);
            dma16(kbase + ksn * H + koffB, &sK[buf ^ 1][32 + w * 8][0]);
            dma16(vbase + ksn + voffA, &sVt[buf ^ 1][w * 8][0]);
            dma16(vbase + ksn + voffB, &sVt[buf ^ 1][32 + w * 8][0]);
        }

        const int s0 = jt * 64;
        const bool diag = (jt == qt);
        #pragma unroll
        for (int nt = 0; nt < 4; ++nt) {
            f32x4 sacc = f32x4{0.f, 0.f, 0.f, 0.f};
            __builtin_amdgcn_s_setprio(1);
            sacc = MFMA16(aq0, *(const bf16x8*)&sK[buf][nt * 16 + ml][(quad ^ mx) << 3], sacc);
            sacc = MFMA16(aq1, *(const bf16x8*)&sK[buf][nt * 16 + ml][((4 + quad) ^ mx) << 3], sacc);
            __builtin_amdgcn_s_setprio(0);
            const int col = s0 + nt * 16 + ml;
            #pragma unroll
            for (int rr = 0; rr < 4; ++rr) {
                const float p = (diag && col > trow + rr) ? 0.f : exp2f(sacc[rr]);
                lrow[rr] += p;
                const int row = quad * 4 + rr;
                const int sw  = (row & 7) ^ ((row & 8) >> 2);
                sP[w][row][(((nt * 2 + (ml >> 3)) ^ sw) << 3) | (ml & 7)] = (bf16)p;
            }
        }
        asm volatile("s_waitcnt lgkmcnt(0)" ::: "memory");
        __builtin_amdgcn_sched_barrier(0);

        __builtin_amdgcn_s_setprio(1);
        #pragma unroll
        for (int ks = 0; ks < 2; ++ks) {
            const int pch = ((ks * 4 + quad) ^ (ml & 7) ^ ((ml & 8) >> 2)) << 3;
            const bf16x8 ap = *(const bf16x8*)&sP[w][ml][pch];
            #pragma unroll
            for (int ht = 0; ht < 4; ++ht)
                O[ht] = MFMA16(ap,
                    *(const bf16x8*)&sVt[buf][ht * 16 + ml][(((ks << 2) + quad) ^ mx) << 3],
                    O[ht]);
        }
        __builtin_amdgcn_s_setprio(0);

        buf ^= 1;
    }

    #pragma unroll
    for (int d = 1; d < 16; d <<= 1)
        #pragma unroll
        for (int rr = 0; rr < 4; ++rr)
            lrow[rr] += __shfl_xor(lrow[rr], d, 64);

    if (g == 0) {
        // single chunk: normalize in registers, write final output directly
        float inv[4];
        #pragma unroll
        for (int rr = 0; rr < 4; ++rr) inv[rr] = 1.f / lrow[rr];
        float* op = out + ((long)b * T + t0 + w * 16 + quad * 4) * H;
        #pragma unroll
        for (int ht = 0; ht < 4; ++ht)
            #pragma unroll
            for (int rr = 0; rr < 4; ++rr)
                op[rr * H + ht * 16 + ml] = O[ht][rr] * inv[rr];
        return;
    }

    const long slot0 = (long)b * SLOTS_PER_B + (long)(g + 1) * (4 * g + r);
    const long slot  = slot0 + c;
    float* po = pO + slot * 4096 + (w * 16) * 64;
    #pragma unroll
    for (int ht = 0; ht < 4; ++ht)
        #pragma unroll
        for (int rr = 0; rr < 4; ++rr)
            po[(quad * 4 + rr) * 64 + ht * 16 + ml] = O[ht][rr];
    if (ml == 0) {
        #pragma unroll
        for (int rr = 0; rr < 4; ++rr)
            pL[slot * 64 + w * 16 + quad * 4 + rr] = lrow[rr];
    }

    // release own chunk, then check arrival count
    __threadfence();
    if (tid == 0) s_old = atomicAdd(&cnt[b * 64 + qt], 1);
    __syncthreads();
    if (s_old != g) return;          // not the last chunk to finish

    // last arrival: acquire others' writes and reduce in chunk-index order
    __threadfence();
    const int row = tid >> 2;
    const int q4  = tid & 3;
    f32x4 o[4];
    #pragma unroll
    for (int j = 0; j < 4; ++j) o[j] = f32x4{0.f, 0.f, 0.f, 0.f};
    float l = 0.f;
    for (int cc = 0; cc <= g; ++cc) {
        const float* pp = pO + (slot0 + cc) * 4096 + row * 64 + q4 * 16;
        #pragma unroll
        for (int j = 0; j < 4; ++j) o[j] += *(const f32x4*)(pp + j * 4);
        l += pL[(slot0 + cc) * 64 + row];
    }
    const float inv = 1.f / l;
    float* op = out + ((long)b * T + qt * 64 + row) * H + q4 * 16;
    #pragma unroll
    for (int j = 0; j < 4; ++j) {
        f32x4 v = o[j];
        v[0] *= inv; v[1] *= inv; v[2] *= inv; v[3] *= inv;
        *(f32x4*)(op + j * 4) = v;
    }
}

// ---------------------------------------------------------------------------
extern "C" void kernel_launch(void* const* d_in, const int* in_sizes, int n_in,
                              void* d_out, int out_size, void* d_ws, size_t ws_size,
                              hipStream_t stream) {
    const float* x  = (const float*)d_in[0];
    const float* Wq = (const float*)d_in[1];
    const float* Wk = (const float*)d_in[2];
    const float* Wv = (const float*)d_in[3];
    float* out = (float*)d_out;

    char* ws = (char*)d_ws;
    const size_t WT_BYTES = (size_t)NG * Cd * sizeof(bf16);
    const size_t QK_BYTES = (size_t)Bn * T * H * sizeof(bf16);
    const size_t PO_OFF   = WT_BYTES + 3 * QK_BYTES;
    const size_t PO_BYTES = (size_t)Bn * SLOTS_PER_B * 4096 * sizeof(float);
    const size_t PL_BYTES = (size_t)Bn * SLOTS_PER_B * 64 * sizeof(float);
    bf16*  Wt  = (bf16*)ws;
    bf16*  qw  = (bf16*)(ws + WT_BYTES);
    bf16*  kw  = (bf16*)(ws + WT_BYTES + QK_BYTES);
    bf16*  vtw = (bf16*)(ws + WT_BYTES + 2 * QK_BYTES);
    float* pO  = (float*)(ws + PO_OFF);
    float* pL  = (float*)(ws + PO_OFF + PO_BYTES);
    int*   cnt = (int*)(ws + PO_OFF + PO_BYTES + PL_BYTES);

    wt_kernel<<<dim3(16, 3), dim3(256), 0, stream>>>(Wq, Wk, Wv, Wt, cnt);
    proj_kernel<<<dim3((Bn * T) / 32), dim3(512), 0, stream>>>(x, Wt, qw, kw, vtw);
    attn_kernel<<<dim3(36, CH, Bn), dim3(256), 0, stream>>>(qw, kw, vtw, pO, pL, cnt, out);
}

// Round 5
// 150.877 us; speedup vs baseline: 2.2737x; 2.2737x over previous
//
#include <hip/hip_runtime.h>
#include <hip/hip_bf16.h>

typedef __bf16 bf16;
typedef __bf16 bf16x8 __attribute__((ext_vector_type(8)));
typedef __bf16 bf16x4 __attribute__((ext_vector_type(4)));
typedef float  f32x4  __attribute__((ext_vector_type(4)));

#define MFMA16(A, B, C) __builtin_amdgcn_mfma_f32_16x16x32_bf16((A), (B), (C), 0, 0, 0)

static constexpr int Bn = 4;
static constexpr int T  = 4096;
static constexpr int Cd = 1024;
static constexpr int H  = 64;
static constexpr int NG = 192;
static constexpr int CH = 8;            // K-tiles (64 keys each) per split-K chunk
static constexpr int SLOTS_PER_B = 288; // sum_{qt=0..63} ceil((qt+1)/8)
// q pre-scale: 1/sqrt(C) * log2(e) so attn can use v_exp_f32 (2^x) directly
static constexpr float QSCALE = 0.045084220f;

// async global->LDS DMA, 16B per lane; LDS dest = wave-uniform base + lane*16
__device__ inline void dma16(const void* g, void* l) {
    __builtin_amdgcn_global_load_lds(
        (const __attribute__((address_space(1))) unsigned int*)g,
        (__attribute__((address_space(3))) unsigned int*)l, 16, 0, 0);
}

// compile-time-constant counted vmcnt (folds to one instruction after unroll)
__device__ __forceinline__ void waitcnt_vm(int n) {
    if (n == 0)      asm volatile("s_waitcnt vmcnt(0)" ::: "memory");
    else if (n == 1) asm volatile("s_waitcnt vmcnt(1)" ::: "memory");
    else             asm volatile("s_waitcnt vmcnt(2)" ::: "memory");
}

__device__ inline bf16x8 cvt_bf16x8(float4 a, float4 b) {
    bf16x8 r;
    r[0] = (bf16)a.x; r[1] = (bf16)a.y; r[2] = (bf16)a.z; r[3] = (bf16)a.w;
    r[4] = (bf16)b.x; r[5] = (bf16)b.y; r[6] = (bf16)b.z; r[7] = (bf16)b.w;
    return r;
}

// ---------------------------------------------------------------------------
// Kernel 1: coalesced transpose W=[Wq|Wk|Wv] ([C][H] fp32) -> Wt[192][1024] bf16
// ---------------------------------------------------------------------------
__global__ __launch_bounds__(256) void wt_kernel(const float* __restrict__ Wq,
                                                 const float* __restrict__ Wk,
                                                 const float* __restrict__ Wv,
                                                 bf16* __restrict__ Wt) {
    __shared__ float s[64][65];
    const int cb = blockIdx.x;
    const int m  = blockIdx.y;
    const float* W = (m == 0) ? Wq : (m == 1) ? Wk : Wv;
    for (int i = threadIdx.x; i < 64 * 64; i += 256) {
        const int c = i >> 6, h = i & 63;
        s[c][h] = W[(cb * 64 + c) * H + h];
    }
    __syncthreads();
    for (int i = threadIdx.x; i < 64 * 64; i += 256) {
        const int n = i >> 6, c = i & 63;
        Wt[(m * 64 + n) * Cd + cb * 64 + c] = (bf16)s[c][n];
    }
}

// ---------------------------------------------------------------------------
// Kernel 2: QKV projection v8. grid = 512 blocks, 512 thr = 8 waves (2x4).
// Single barrier per K-step, counted vmcnt, 4-slot x ring, 2-deep Wt.
// ---------------------------------------------------------------------------
__global__ __launch_bounds__(512, 4) void proj_kernel(const float* __restrict__ x,
                                                      const bf16* __restrict__ Wt,
                                                      bf16* __restrict__ qw,
                                                      bf16* __restrict__ kw,
                                                      bf16* __restrict__ vtw) {
    const int tid  = threadIdx.x;
    const int lane = tid & 63;
    const int w    = tid >> 6;       // 0..7
    const int wr   = w >> 2;         // 0..1 row-group
    const int wc   = w & 3;          // 0..3 col-group
    const int ml   = lane & 15;
    const int quad = lane >> 4;

    const long r0 = (long)blockIdx.x * 32;

    __shared__ float sX[4][32][64];   // 8 KB/slot x4, 16B chunks swizzled c^(r&15)
    __shared__ bf16  sW[2][192][64];  // 24 KB/buf x2, 16B chunks swizzled c^(r&7)

    const int xrow = w * 4 + (lane >> 4);           // 0..31
    const float* gx = x + (r0 + xrow) * Cd + (((lane & 15) ^ (xrow & 15)) << 2);
    const int wchunk = ((lane & 7) ^ (lane >> 3)) << 3;   // elem offset in tile
    const bf16* gw0 = Wt + (long)(w * 24 + 0 + (lane >> 3)) * Cd + wchunk;
    const bf16* gw1 = Wt + (long)(w * 24 + 8 + (lane >> 3)) * Cd + wchunk;
    const bf16* gw2 = Wt + (long)(w * 24 + 16 + (lane >> 3)) * Cd + wchunk;

    f32x4 acc[3];
    #pragma unroll
    for (int j = 0; j < 3; ++j) acc[j] = f32x4{0.f, 0.f, 0.f, 0.f};

    // prologue issue order matters for vmcnt accounting: x(0), w(0)x3, x(1), x(2)
    dma16(gx, &sX[0][w * 4][0]);
    dma16(gw0, &sW[0][w * 24 + 0][0]);
    dma16(gw1, &sW[0][w * 24 + 8][0]);
    dma16(gw2, &sW[0][w * 24 + 16][0]);
    dma16(gx + 64,  &sX[1][w * 4][0]);
    dma16(gx + 128, &sX[2][w * 4][0]);

    const int arow = wr * 16 + ml;                  // A row in tile
    const int brow0 = wc * 48 + ml;                 // B rows in tile (f*16 +)
    const int bsw = ml & 7;

    #pragma unroll
    for (int t = 0; t < 16; ++t) {
        waitcnt_vm(t == 0 ? 2 : (t <= 13 ? 1 : 0));
        __builtin_amdgcn_sched_barrier(0);
        __builtin_amdgcn_s_barrier();           // tile t ready in all waves
        __builtin_amdgcn_sched_barrier(0);

        // issue next tiles AFTER the barrier: the barrier separates these
        // writes from last iteration's reads of the same buffers.
        if (t + 1 < 16) {
            dma16(gw0 + (t + 1) * 64, &sW[(t + 1) & 1][w * 24 + 0][0]);
            dma16(gw1 + (t + 1) * 64, &sW[(t + 1) & 1][w * 24 + 8][0]);
            dma16(gw2 + (t + 1) * 64, &sW[(t + 1) & 1][w * 24 + 16][0]);
        }
        if (t + 3 < 16) dma16(gx + (t + 3) * 64, &sX[(t + 3) & 3][w * 4][0]);

        const int bx = t & 3, bw = t & 1;
        __builtin_amdgcn_s_setprio(1);
        #pragma unroll
        for (int ks = 0; ks < 2; ++ks) {
            const int ca = (ks * 8 + quad * 2) ^ ml;       // A chunk (of 16)
            const float4 lo = *(const float4*)&sX[bx][arow][ca << 2];
            const float4 hi = *(const float4*)&sX[bx][arow][(ca ^ 1) << 2];
            const bf16x8 af = cvt_bf16x8(lo, hi);
            const int cb0 = (ks * 4 + quad) ^ bsw;         // B chunk (of 8)
            acc[0] = MFMA16(af, *(const bf16x8*)&sW[bw][brow0 + 0][cb0 << 3], acc[0]);
            acc[1] = MFMA16(af, *(const bf16x8*)&sW[bw][brow0 + 16][cb0 << 3], acc[1]);
            acc[2] = MFMA16(af, *(const bf16x8*)&sW[bw][brow0 + 32][cb0 << 3], acc[2]);
        }
        __builtin_amdgcn_s_setprio(0);
    }

    const int b = (int)(r0 >> 12);
    const long rowb = r0 + wr * 16 + quad * 4;
    const int  tloc = (int)(rowb & 4095);

    #pragma unroll
    for (int f = 0; f < 3; ++f) {
        const int base = wc * 48 + f * 16;
        const int sel  = base >> 6;
        const int h    = (base & 63) + ml;
        if (sel == 0) {
            #pragma unroll
            for (int rr = 0; rr < 4; ++rr)
                qw[(rowb + rr) * H + h] = (bf16)(acc[f][rr] * QSCALE);
        } else if (sel == 1) {
            #pragma unroll
            for (int rr = 0; rr < 4; ++rr)
                kw[(rowb + rr) * H + h] = (bf16)acc[f][rr];
        } else {
            bf16x4 pv;
            #pragma unroll
            for (int rr = 0; rr < 4; ++rr) pv[rr] = (bf16)acc[f][rr];
            *(bf16x4*)(vtw + ((long)(b * H + h)) * T + tloc) = pv;
        }
    }
}

// ---------------------------------------------------------------------------
// Kernel 3: split-K causal flash chunk v5 (separate combine — NO device
// fences: cross-XCD fencing invalidates L2 and regressed 2.2x in R4).
// ---------------------------------------------------------------------------
__global__ __launch_bounds__(256, 4) void attn_kernel(const bf16* __restrict__ qw,
                                                      const bf16* __restrict__ kw,
                                                      const bf16* __restrict__ vtw,
                                                      float* __restrict__ pO,
                                                      float* __restrict__ pL) {
    // triangular decode: u in [0,36) -> (g, c) with c <= g
    const int u = blockIdx.x;
    int g = 0;
    #pragma unroll
    for (int gg = 1; gg < 8; ++gg) if (u >= (gg * (gg + 1)) / 2) g = gg;
    const int c  = u - (g * (g + 1)) / 2;
    const int r  = blockIdx.y;
    const int b  = blockIdx.z;
    const int qt = g * 8 + r;

    const int tid  = threadIdx.x;
    const int lane = tid & 63;
    const int w    = tid >> 6;
    const int ml   = lane & 15;
    const int quad = lane >> 4;
    const int mx   = ml & 7;

    __shared__ bf16 sK[2][64][64];    // 16 KB
    __shared__ bf16 sVt[2][64][64];   // 16 KB
    __shared__ bf16 sP[4][16][64];    // 8 KB, XOR chunk-swizzled (no pad)

    const int t0 = qt * 64;

    const bf16* q0 = qw + ((long)b * T + t0 + w * 16 + ml) * H;
    const bf16x8 aq0 = *(const bf16x8*)(q0 + quad * 8);
    const bf16x8 aq1 = *(const bf16x8*)(q0 + 32 + quad * 8);

    f32x4 O[4];
    #pragma unroll
    for (int ht = 0; ht < 4; ++ht) O[ht] = f32x4{0.f, 0.f, 0.f, 0.f};
    float lrow[4] = {0.f, 0.f, 0.f, 0.f};

    const int trow = t0 + w * 16 + quad * 4;
    const int jt0 = c * CH;
    const int jt1 = (c == g) ? qt + 1 : (c + 1) * CH;

    const int drow = w * 8 + (lane >> 3);
    const int dsw  = ((lane & 7) ^ (drow & 7)) << 3;
    const bf16* kbase = kw + (long)b * T * H;
    const bf16* vbase = vtw + (long)b * H * T;
    const long koffA = (long)drow * H + dsw;
    const long koffB = koffA + 32 * H;
    const long voffA = (long)drow * T + dsw;
    const long voffB = voffA + (long)32 * T;

    {   // prologue: issue tile jt0 (4 DMA per wave; waited inside the loop)
        const long ks0 = (long)jt0 * 64;
        dma16(kbase + ks0 * H + koffA, &sK[0][w * 8][0]);
        dma16(kbase + ks0 * H + koffB, &sK[0][32 + w * 8][0]);
        dma16(vbase + ks0 + voffA, &sVt[0][w * 8][0]);
        dma16(vbase + ks0 + voffB, &sVt[0][32 + w * 8][0]);
    }

    int buf = 0;
    for (int jt = jt0; jt < jt1; ++jt) {
        // own-wave DMAs retired, then barrier => tile jt staged across waves
        asm volatile("s_waitcnt vmcnt(0)" ::: "memory");
        __builtin_amdgcn_sched_barrier(0);
        __builtin_amdgcn_s_barrier();
        __builtin_amdgcn_sched_barrier(0);

        // issue next tile AFTER the barrier (barrier guards reuse of buf^1)
        if (jt + 1 < jt1) {
            const long ksn = (long)(jt + 1) * 64;
            dma16(kbase + ksn * H + koffA, &sK[buf ^ 1][w * 8][0]);
            dma16(kbase + ksn * H + koffB, &sK[buf ^ 1][32 + w * 8][0]);
            dma16(vbase + ksn + voffA, &sVt[buf ^ 1][w * 8][0]);
            dma16(vbase + ksn + voffB, &sVt[buf ^ 1][32 + w * 8][0]);
        }

        const int s0 = jt * 64;
        const bool diag = (jt == qt);
        #pragma unroll
        for (int nt = 0; nt < 4; ++nt) {
            f32x4 sacc = f32x4{0.f, 0.f, 0.f, 0.f};
            __builtin_amdgcn_s_setprio(1);
            sacc = MFMA16(aq0, *(const bf16x8*)&sK[buf][nt * 16 + ml][(quad ^ mx) << 3], sacc);
            sacc = MFMA16(aq1, *(const bf16x8*)&sK[buf][nt * 16 + ml][((4 + quad) ^ mx) << 3], sacc);
            __builtin_amdgcn_s_setprio(0);
            const int col = s0 + nt * 16 + ml;
            #pragma unroll
            for (int rr = 0; rr < 4; ++rr) {
                const float p = (diag && col > trow + rr) ? 0.f : exp2f(sacc[rr]);
                lrow[rr] += p;
                const int row = quad * 4 + rr;
                const int sw  = (row & 7) ^ ((row & 8) >> 2);
                sP[w][row][(((nt * 2 + (ml >> 3)) ^ sw) << 3) | (ml & 7)] = (bf16)p;
            }
        }
        asm volatile("s_waitcnt lgkmcnt(0)" ::: "memory");
        __builtin_amdgcn_sched_barrier(0);

        __builtin_amdgcn_s_setprio(1);
        #pragma unroll
        for (int ks = 0; ks < 2; ++ks) {
            const int pch = ((ks * 4 + quad) ^ (ml & 7) ^ ((ml & 8) >> 2)) << 3;
            const bf16x8 ap = *(const bf16x8*)&sP[w][ml][pch];
            #pragma unroll
            for (int ht = 0; ht < 4; ++ht)
                O[ht] = MFMA16(ap,
                    *(const bf16x8*)&sVt[buf][ht * 16 + ml][(((ks << 2) + quad) ^ mx) << 3],
                    O[ht]);
        }
        __builtin_amdgcn_s_setprio(0);

        buf ^= 1;
    }

    #pragma unroll
    for (int d = 1; d < 16; d <<= 1)
        #pragma unroll
        for (int rr = 0; rr < 4; ++rr)
            lrow[rr] += __shfl_xor(lrow[rr], d, 64);

    const long slot = (long)b * SLOTS_PER_B + (long)(g + 1) * (4 * g + r) + c;
    float* po = pO + slot * 4096 + (w * 16) * 64;
    #pragma unroll
    for (int ht = 0; ht < 4; ++ht)
        #pragma unroll
        for (int rr = 0; rr < 4; ++rr)
            po[(quad * 4 + rr) * 64 + ht * 16 + ml] = O[ht][rr];
    if (ml == 0) {
        #pragma unroll
        for (int rr = 0; rr < 4; ++rr)
            pL[slot * 64 + w * 16 + quad * 4 + rr] = lrow[rr];
    }
}

// ---------------------------------------------------------------------------
// Kernel 4: combine partials. grid (64 qt, 4 b), 256 thr.
// ---------------------------------------------------------------------------
__global__ __launch_bounds__(256) void combine_kernel(const float* __restrict__ pO,
                                                      const float* __restrict__ pL,
                                                      float* __restrict__ out) {
    const int qt = blockIdx.x;
    const int b  = blockIdx.y;
    const int g  = qt >> 3, r = qt & 7;
    const int nch = g + 1;
    const long slot0 = (long)b * SLOTS_PER_B + (long)(g + 1) * (4 * g + r);

    const int tid = threadIdx.x;
    const int row = tid >> 2;
    const int q4  = tid & 3;

    f32x4 o[4];
    #pragma unroll
    for (int j = 0; j < 4; ++j) o[j] = f32x4{0.f, 0.f, 0.f, 0.f};
    float l = 0.f;

    for (int cc = 0; cc < nch; ++cc) {
        const float* po = pO + (slot0 + cc) * 4096 + row * 64 + q4 * 16;
        #pragma unroll
        for (int j = 0; j < 4; ++j) o[j] += *(const f32x4*)(po + j * 4);
        l += pL[(slot0 + cc) * 64 + row];
    }
    const float inv = 1.f / l;
    float* op = out + ((long)b * T + qt * 64 + row) * H + q4 * 16;
    #pragma unroll
    for (int j = 0; j < 4; ++j) {
        f32x4 v = o[j];
        v[0] *= inv; v[1] *= inv; v[2] *= inv; v[3] *= inv;
        *(f32x4*)(op + j * 4) = v;
    }
}

// ---------------------------------------------------------------------------
extern "C" void kernel_launch(void* const* d_in, const int* in_sizes, int n_in,
                              void* d_out, int out_size, void* d_ws, size_t ws_size,
                              hipStream_t stream) {
    const float* x  = (const float*)d_in[0];
    const float* Wq = (const float*)d_in[1];
    const float* Wk = (const float*)d_in[2];
    const float* Wv = (const float*)d_in[3];
    float* out = (float*)d_out;

    char* ws = (char*)d_ws;
    const size_t WT_BYTES = (size_t)NG * Cd * sizeof(bf16);
    const size_t QK_BYTES = (size_t)Bn * T * H * sizeof(bf16);
    const size_t PO_OFF   = WT_BYTES + 3 * QK_BYTES;
    const size_t PO_BYTES = (size_t)Bn * SLOTS_PER_B * 4096 * sizeof(float);
    bf16*  Wt  = (bf16*)ws;
    bf16*  qw  = (bf16*)(ws + WT_BYTES);
    bf16*  kw  = (bf16*)(ws + WT_BYTES + QK_BYTES);
    bf16*  vtw = (bf16*)(ws + WT_BYTES + 2 * QK_BYTES);
    float* pO  = (float*)(ws + PO_OFF);
    float* pL  = (float*)(ws + PO_OFF + PO_BYTES);

    wt_kernel<<<dim3(16, 3), dim3(256), 0, stream>>>(Wq, Wk, Wv, Wt);
    proj_kernel<<<dim3((Bn * T) / 32), dim3(512), 0, stream>>>(x, Wt, qw, kw, vtw);
    attn_kernel<<<dim3(36, CH, Bn), dim3(256), 0, stream>>>(qw, kw, vtw, pO, pL);
    combine_kernel<<<dim3(T / 64, Bn), dim3(256), 0, stream>>>(pO, pL, out);
}